// Round 4
// baseline (2088.000 us; speedup 1.0000x reference)
//
#include <hip/hip_runtime.h>
#include <hip/hip_bf16.h>

// Problem constants (fixed by setup_inputs)
#define Bn 16
#define Nn 4096
#define Pn 1024
#define Sn 32
#define Cn 64
#define EPSn 1e-5f
#define ALPHAn 0.2f

// Folded-weight table in module device memory (avoids any d_ws sizing doubt).
#define W1T_OFF 0      // [67][64]
#define B1_OFF  4288   // [64]
#define W2T_OFF 4352   // [64][64]
#define B2_OFF  8448   // [64]
#define W3T_OFF 8512   // [64][128]
#define B3_OFF  16704  // [128]
#define AT_OFF  16832  // [131][128]
#define WS_FLOATS 33600

__device__ float g_W[WS_FLOATS];

// Inputs fp32 (R2->R3: NaN vanished when reading fp32 => 4-byte storage).
// Output fp32 (R3: bf16-packed writes gave interleaved-garbage signature 5.59).
__global__ void prep_kernel(
    const float* __restrict__ w1, const float* __restrict__ b1,
    const float* __restrict__ g1, const float* __restrict__ bt1,
    const float* __restrict__ m1, const float* __restrict__ v1,
    const float* __restrict__ w2, const float* __restrict__ b2,
    const float* __restrict__ g2, const float* __restrict__ bt2,
    const float* __restrict__ m2, const float* __restrict__ v2,
    const float* __restrict__ w3, const float* __restrict__ b3,
    const float* __restrict__ g3, const float* __restrict__ bt3,
    const float* __restrict__ m3, const float* __restrict__ v3,
    const float* __restrict__ a)
{
  float* __restrict__ W = g_W;
  const int idx = blockIdx.x * blockDim.x + threadIdx.x;
  if (idx >= WS_FLOATS) return;
  if (idx < B1_OFF) {                       // w1 transposed+scaled
    const int i = idx >> 6, o = idx & 63;
    const float s = g1[o] * rsqrtf(v1[o] + EPSn);
    W[idx] = w1[o * 67 + i] * s;
  } else if (idx < W2T_OFF) {               // b1 folded
    const int o = idx - B1_OFF;
    const float s = g1[o] * rsqrtf(v1[o] + EPSn);
    W[idx] = (b1[o] - m1[o]) * s + bt1[o];
  } else if (idx < B2_OFF) {                // w2
    const int r = idx - W2T_OFF;
    const int i = r >> 6, o = r & 63;
    const float s = g2[o] * rsqrtf(v2[o] + EPSn);
    W[idx] = w2[o * 64 + i] * s;
  } else if (idx < W3T_OFF) {               // b2
    const int o = idx - B2_OFF;
    const float s = g2[o] * rsqrtf(v2[o] + EPSn);
    W[idx] = (b2[o] - m2[o]) * s + bt2[o];
  } else if (idx < B3_OFF) {                // w3
    const int r = idx - W3T_OFF;
    const int i = r >> 7, o = r & 127;
    const float s = g3[o] * rsqrtf(v3[o] + EPSn);
    W[idx] = w3[o * 64 + i] * s;
  } else if (idx < AT_OFF) {                // b3
    const int o = idx - B3_OFF;
    const float s = g3[o] * rsqrtf(v3[o] + EPSn);
    W[idx] = (b3[o] - m3[o]) * s + bt3[o];
  } else {                                  // a copy
    W[idx] = a[idx - AT_OFF];
  }
}

// One block per (b,p) group. 256 threads.
__global__ __launch_bounds__(256) void fused_kernel(
    const float* __restrict__ xyz, const float* __restrict__ points,
    const int* __restrict__ fps_idx, const int* __restrict__ group_idx,
    float* __restrict__ out)
{
  const float* __restrict__ W = g_W;
  // odd strides (69/65/129) -> conflict-free column access with lanes along s
  __shared__ float sA[32 * 69];    // input concat (67 ch); reused as h2 (stride 65)
  __shared__ float sB[32 * 65];    // h1
  __shared__ float sH3[32 * 129];  // layer-3 output (128 ch)
  __shared__ float sE[32 * 129];   // attention scores
  __shared__ float sFps[68];       // [0..2]=new_xyz, [3..66]=fps feat
  __shared__ float sRx[96];        // relative xyz [s*3+d]
  __shared__ float sF1[64], sF2[64], sF3[128];
  __shared__ float sEb[128];       // ebias for attention

  const int t = threadIdx.x;
  const int bp = blockIdx.x;
  const int b = bp >> 10;
  const int p = bp & 1023;

  // -------- Phase 0a: fps point (new_xyz + fps feat) --------
  if (t < 67) {
    const int fi = fps_idx[b * Pn + p];
    float v;
    if (t < 3) v = xyz[b * 3 * Nn + t * Nn + fi];
    else       v = points[b * Cn * Nn + (t - 3) * Nn + fi];
    sFps[t] = v;
  }
  __syncthreads();

  // -------- Phase 0b: gather neighbors (rel xyz || feat) --------
  {
    const int s0 = t >> 3, cg = t & 7;
    const int gi = group_idx[(b * Pn + p) * Sn + s0];
    const float* prow = points + b * Cn * Nn + gi;
    const int c0 = cg * 8;
    #pragma unroll
    for (int k = 0; k < 8; ++k)
      sA[s0 * 69 + 3 + c0 + k] = prow[(c0 + k) * Nn];
    if (cg == 0) {
      #pragma unroll
      for (int d = 0; d < 3; ++d) {
        const float r = xyz[b * 3 * Nn + d * Nn + gi] - sFps[d];
        sA[s0 * 69 + d] = r;
        sRx[s0 * 3 + d] = r;
      }
    }
  }
  __syncthreads();

  const int s = t & 31;
  const int og = t >> 5;
  const int o0 = og * 8;

  // -------- Phase 1: layer1 (67 -> 64), relu --------
  {
    float acc[8];
    {
      const float4 bb0 = *(const float4*)(W + B1_OFF + o0);
      const float4 bb1 = *(const float4*)(W + B1_OFF + o0 + 4);
      acc[0] = bb0.x; acc[1] = bb0.y; acc[2] = bb0.z; acc[3] = bb0.w;
      acc[4] = bb1.x; acc[5] = bb1.y; acc[6] = bb1.z; acc[7] = bb1.w;
    }
    #pragma unroll 4
    for (int i = 0; i < 67; ++i) {
      const float v = sA[s * 69 + i];
      const float4 wa = *(const float4*)(W + W1T_OFF + i * 64 + o0);
      const float4 wb = *(const float4*)(W + W1T_OFF + i * 64 + o0 + 4);
      acc[0] = fmaf(v, wa.x, acc[0]); acc[1] = fmaf(v, wa.y, acc[1]);
      acc[2] = fmaf(v, wa.z, acc[2]); acc[3] = fmaf(v, wa.w, acc[3]);
      acc[4] = fmaf(v, wb.x, acc[4]); acc[5] = fmaf(v, wb.y, acc[5]);
      acc[6] = fmaf(v, wb.z, acc[6]); acc[7] = fmaf(v, wb.w, acc[7]);
    }
    #pragma unroll
    for (int k = 0; k < 8; ++k) sB[s * 65 + o0 + k] = fmaxf(acc[k], 0.f);
  }
  if (t < 64) {  // fps row, layer1 (wave 0)
    float acc = W[B1_OFF + t];
    for (int i = 0; i < 67; ++i) acc = fmaf(sFps[i], W[W1T_OFF + i * 64 + t], acc);
    sF1[t] = fmaxf(acc, 0.f);
  }
  __syncthreads();

  // -------- Phase 2: layer2 (64 -> 64), relu  (sB -> sA stride 65) --------
  {
    float acc[8];
    {
      const float4 bb0 = *(const float4*)(W + B2_OFF + o0);
      const float4 bb1 = *(const float4*)(W + B2_OFF + o0 + 4);
      acc[0] = bb0.x; acc[1] = bb0.y; acc[2] = bb0.z; acc[3] = bb0.w;
      acc[4] = bb1.x; acc[5] = bb1.y; acc[6] = bb1.z; acc[7] = bb1.w;
    }
    #pragma unroll 4
    for (int i = 0; i < 64; ++i) {
      const float v = sB[s * 65 + i];
      const float4 wa = *(const float4*)(W + W2T_OFF + i * 64 + o0);
      const float4 wb = *(const float4*)(W + W2T_OFF + i * 64 + o0 + 4);
      acc[0] = fmaf(v, wa.x, acc[0]); acc[1] = fmaf(v, wa.y, acc[1]);
      acc[2] = fmaf(v, wa.z, acc[2]); acc[3] = fmaf(v, wa.w, acc[3]);
      acc[4] = fmaf(v, wb.x, acc[4]); acc[5] = fmaf(v, wb.y, acc[5]);
      acc[6] = fmaf(v, wb.z, acc[6]); acc[7] = fmaf(v, wb.w, acc[7]);
    }
    #pragma unroll
    for (int k = 0; k < 8; ++k) sA[s * 65 + o0 + k] = fmaxf(acc[k], 0.f);
  }
  if (t < 64) {
    float acc = W[B2_OFF + t];
    for (int i = 0; i < 64; ++i) acc = fmaf(sF1[i], W[W2T_OFF + i * 64 + t], acc);
    sF2[t] = fmaxf(acc, 0.f);
  }
  __syncthreads();

  // -------- Phase 3: layer3 (64 -> 128), relu  (sA -> sH3 stride 129) --------
  {
    float acc[16];
    {
      const float4 b0 = *(const float4*)(W + B3_OFF + o0);
      const float4 b1 = *(const float4*)(W + B3_OFF + o0 + 4);
      const float4 b2 = *(const float4*)(W + B3_OFF + o0 + 64);
      const float4 b3 = *(const float4*)(W + B3_OFF + o0 + 68);
      acc[0]=b0.x; acc[1]=b0.y; acc[2]=b0.z; acc[3]=b0.w;
      acc[4]=b1.x; acc[5]=b1.y; acc[6]=b1.z; acc[7]=b1.w;
      acc[8]=b2.x; acc[9]=b2.y; acc[10]=b2.z; acc[11]=b2.w;
      acc[12]=b3.x; acc[13]=b3.y; acc[14]=b3.z; acc[15]=b3.w;
    }
    #pragma unroll 2
    for (int i = 0; i < 64; ++i) {
      const float v = sA[s * 65 + i];
      const float* wr = W + W3T_OFF + i * 128;
      const float4 wa = *(const float4*)(wr + o0);
      const float4 wb = *(const float4*)(wr + o0 + 4);
      const float4 wc = *(const float4*)(wr + o0 + 64);
      const float4 wd = *(const float4*)(wr + o0 + 68);
      acc[0]=fmaf(v,wa.x,acc[0]);  acc[1]=fmaf(v,wa.y,acc[1]);
      acc[2]=fmaf(v,wa.z,acc[2]);  acc[3]=fmaf(v,wa.w,acc[3]);
      acc[4]=fmaf(v,wb.x,acc[4]);  acc[5]=fmaf(v,wb.y,acc[5]);
      acc[6]=fmaf(v,wb.z,acc[6]);  acc[7]=fmaf(v,wb.w,acc[7]);
      acc[8]=fmaf(v,wc.x,acc[8]);  acc[9]=fmaf(v,wc.y,acc[9]);
      acc[10]=fmaf(v,wc.z,acc[10]); acc[11]=fmaf(v,wc.w,acc[11]);
      acc[12]=fmaf(v,wd.x,acc[12]); acc[13]=fmaf(v,wd.y,acc[13]);
      acc[14]=fmaf(v,wd.z,acc[14]); acc[15]=fmaf(v,wd.w,acc[15]);
    }
    #pragma unroll
    for (int k = 0; k < 8; ++k) {
      sH3[s * 129 + o0 + k]      = fmaxf(acc[k], 0.f);
      sH3[s * 129 + o0 + 64 + k] = fmaxf(acc[8 + k], 0.f);
    }
  }
  if (t < 128) {  // fps row, layer3 (waves 0-1)
    float acc = W[B3_OFF + t];
    for (int i = 0; i < 64; ++i) acc = fmaf(sF2[i], W[W3T_OFF + i * 128 + t], acc);
    sF3[t] = fmaxf(acc, 0.f);
  }
  __syncthreads();

  // -------- Phase 4: ebias[j] = [new_xyz || fps3] . a[:,j] --------
  if (t < 128) {
    float acc = 0.f;
    #pragma unroll
    for (int i = 0; i < 3; ++i) acc = fmaf(sFps[i], W[AT_OFF + i * 128 + t], acc);
    for (int i = 0; i < 128; ++i) acc = fmaf(sF3[i], W[AT_OFF + (3 + i) * 128 + t], acc);
    sEb[t] = acc;
  }
  __syncthreads();

  // -------- Phase 5: e = leakyrelu(ebias - [rxyz||h3] . a) --------
  {
    float acc[16];
    #pragma unroll
    for (int k = 0; k < 16; ++k) acc[k] = 0.f;
    #pragma unroll
    for (int i = 0; i < 3; ++i) {
      const float v = sRx[s * 3 + i];
      const float* wr = W + AT_OFF + i * 128;
      const float4 wa = *(const float4*)(wr + o0);
      const float4 wb = *(const float4*)(wr + o0 + 4);
      const float4 wc = *(const float4*)(wr + o0 + 64);
      const float4 wd = *(const float4*)(wr + o0 + 68);
      acc[0]=fmaf(v,wa.x,acc[0]);  acc[1]=fmaf(v,wa.y,acc[1]);
      acc[2]=fmaf(v,wa.z,acc[2]);  acc[3]=fmaf(v,wa.w,acc[3]);
      acc[4]=fmaf(v,wb.x,acc[4]);  acc[5]=fmaf(v,wb.y,acc[5]);
      acc[6]=fmaf(v,wb.z,acc[6]);  acc[7]=fmaf(v,wb.w,acc[7]);
      acc[8]=fmaf(v,wc.x,acc[8]);  acc[9]=fmaf(v,wc.y,acc[9]);
      acc[10]=fmaf(v,wc.z,acc[10]); acc[11]=fmaf(v,wc.w,acc[11]);
      acc[12]=fmaf(v,wd.x,acc[12]); acc[13]=fmaf(v,wd.y,acc[13]);
      acc[14]=fmaf(v,wd.z,acc[14]); acc[15]=fmaf(v,wd.w,acc[15]);
    }
    #pragma unroll 2
    for (int i = 0; i < 128; ++i) {
      const float v = sH3[s * 129 + i];
      const float* wr = W + AT_OFF + (3 + i) * 128;
      const float4 wa = *(const float4*)(wr + o0);
      const float4 wb = *(const float4*)(wr + o0 + 4);
      const float4 wc = *(const float4*)(wr + o0 + 64);
      const float4 wd = *(const float4*)(wr + o0 + 68);
      acc[0]=fmaf(v,wa.x,acc[0]);  acc[1]=fmaf(v,wa.y,acc[1]);
      acc[2]=fmaf(v,wa.z,acc[2]);  acc[3]=fmaf(v,wa.w,acc[3]);
      acc[4]=fmaf(v,wb.x,acc[4]);  acc[5]=fmaf(v,wb.y,acc[5]);
      acc[6]=fmaf(v,wb.z,acc[6]);  acc[7]=fmaf(v,wb.w,acc[7]);
      acc[8]=fmaf(v,wc.x,acc[8]);  acc[9]=fmaf(v,wc.y,acc[9]);
      acc[10]=fmaf(v,wc.z,acc[10]); acc[11]=fmaf(v,wc.w,acc[11]);
      acc[12]=fmaf(v,wd.x,acc[12]); acc[13]=fmaf(v,wd.y,acc[13]);
      acc[14]=fmaf(v,wd.z,acc[14]); acc[15]=fmaf(v,wd.w,acc[15]);
    }
    #pragma unroll
    for (int k = 0; k < 8; ++k) {
      float e0 = sEb[o0 + k] - acc[k];
      e0 = (e0 > 0.f) ? e0 : ALPHAn * e0;
      sE[s * 129 + o0 + k] = e0;
      float e1 = sEb[o0 + 64 + k] - acc[8 + k];
      e1 = (e1 > 0.f) ? e1 : ALPHAn * e1;
      sE[s * 129 + o0 + 64 + k] = e1;
    }
  }
  __syncthreads();

  // -------- Phase 6: column softmax over s + pooled sum; write outputs --------
  if (t < 128) {
    const int j = t;
    float mx = -3.4e38f;
    for (int si = 0; si < 32; ++si) mx = fmaxf(mx, sE[si * 129 + j]);
    float den = 0.f, pool = 0.f;
    for (int si = 0; si < 32; ++si) {
      const float wv = __expf(sE[si * 129 + j] - mx);
      den += wv;
      pool = fmaf(wv, sH3[si * 129 + j], pool);
    }
    out[Bn * 3 * Pn + (b * 128 + j) * Pn + p] = pool / den;
  } else if (t < 131) {
    const int d = t - 128;
    out[(b * 3 + d) * Pn + p] = sFps[d];
  }
}

extern "C" void kernel_launch(void* const* d_in, const int* in_sizes, int n_in,
                              void* d_out, int out_size, void* d_ws, size_t ws_size,
                              hipStream_t stream) {
  const float* xyz       = (const float*)d_in[0];
  const float* points    = (const float*)d_in[1];
  const int*   fps_idx   = (const int*)d_in[2];
  const int*   group_idx = (const int*)d_in[3];

  prep_kernel<<<(WS_FLOATS + 255) / 256, 256, 0, stream>>>(
      (const float*)d_in[4],  (const float*)d_in[5],
      (const float*)d_in[6],  (const float*)d_in[7],
      (const float*)d_in[8],  (const float*)d_in[9],
      (const float*)d_in[10], (const float*)d_in[11],
      (const float*)d_in[12], (const float*)d_in[13],
      (const float*)d_in[14], (const float*)d_in[15],
      (const float*)d_in[16], (const float*)d_in[17],
      (const float*)d_in[18], (const float*)d_in[19],
      (const float*)d_in[20], (const float*)d_in[21],
      (const float*)d_in[22]);

  fused_kernel<<<Bn * Pn, 256, 0, stream>>>(xyz, points, fps_idx, group_idx,
                                            (float*)d_out);
}

// Round 5
// 1101.810 us; speedup vs baseline: 1.8951x; 1.8951x over previous
//
#include <hip/hip_runtime.h>
#include <hip/hip_bf16.h>

// Problem constants (fixed by setup_inputs)
#define Bn 16
#define Nn 4096
#define Pn 1024
#define Sn 32
#define Cn 64
#define EPSn 1e-5f
#define ALPHAn 0.2f

// Folded-weight table in module device memory.
#define W1T_OFF 0      // [67][64]
#define B1_OFF  4288   // [64]
#define W2T_OFF 4352   // [64][64]
#define B2_OFF  8448   // [64]
#define W3T_OFF 8512   // [64][128]
#define B3_OFF  16704  // [128]
#define AT_OFF  16832  // [131][128]
#define WS_FLOATS 33600

__device__ __align__(16) float g_W[WS_FLOATS];

__global__ void prep_kernel(
    const float* __restrict__ w1, const float* __restrict__ b1,
    const float* __restrict__ g1, const float* __restrict__ bt1,
    const float* __restrict__ m1, const float* __restrict__ v1,
    const float* __restrict__ w2, const float* __restrict__ b2,
    const float* __restrict__ g2, const float* __restrict__ bt2,
    const float* __restrict__ m2, const float* __restrict__ v2,
    const float* __restrict__ w3, const float* __restrict__ b3,
    const float* __restrict__ g3, const float* __restrict__ bt3,
    const float* __restrict__ m3, const float* __restrict__ v3,
    const float* __restrict__ a)
{
  float* __restrict__ W = g_W;
  const int idx = blockIdx.x * blockDim.x + threadIdx.x;
  if (idx >= WS_FLOATS) return;
  if (idx < B1_OFF) {
    const int i = idx >> 6, o = idx & 63;
    const float s = g1[o] * rsqrtf(v1[o] + EPSn);
    W[idx] = w1[o * 67 + i] * s;
  } else if (idx < W2T_OFF) {
    const int o = idx - B1_OFF;
    const float s = g1[o] * rsqrtf(v1[o] + EPSn);
    W[idx] = (b1[o] - m1[o]) * s + bt1[o];
  } else if (idx < B2_OFF) {
    const int r = idx - W2T_OFF;
    const int i = r >> 6, o = r & 63;
    const float s = g2[o] * rsqrtf(v2[o] + EPSn);
    W[idx] = w2[o * 64 + i] * s;
  } else if (idx < W3T_OFF) {
    const int o = idx - B2_OFF;
    const float s = g2[o] * rsqrtf(v2[o] + EPSn);
    W[idx] = (b2[o] - m2[o]) * s + bt2[o];
  } else if (idx < B3_OFF) {
    const int r = idx - W3T_OFF;
    const int i = r >> 7, o = r & 127;
    const float s = g3[o] * rsqrtf(v3[o] + EPSn);
    W[idx] = w3[o * 64 + i] * s;
  } else if (idx < AT_OFF) {
    const int o = idx - B3_OFF;
    const float s = g3[o] * rsqrtf(v3[o] + EPSn);
    W[idx] = (b3[o] - m3[o]) * s + bt3[o];
  } else {
    W[idx] = a[idx - AT_OFF];
  }
}

// LDS layout (floats). sE aliases the dead sA+sB region in phase 5/6.
#define OFF_A   0       // 32*69 = 2208  (phase-1 input; phase-2 out h2 @stride 65)
#define OFF_B   2208    // 32*65 = 2080  (h1)
#define OFF_E   0       // 32*129 = 4128 aliased over A+B (4288)
#define OFF_H3  4288    // 32*129 = 4128
#define OFF_WB  8416    // 4480 weight staging buffer (max chunk 35*128)
#define OFF_FPS 12896   // 68
#define OFF_RX  12964   // 96
#define OFF_F1  13060   // 64
#define OFF_F2  13124   // 64
#define OFF_F3  13188   // 128
#define OFF_EB  13316   // 128
#define SH_FLOATS 13444 // 53776 B -> 3 blocks/CU (161328 <= 163840)

__device__ __forceinline__ void stage(float* __restrict__ dst,
                                      const float* __restrict__ src,
                                      int count, int t) {
  for (int j = 4 * t; j < count; j += 1024)
    *(float4*)(dst + j) = *(const float4*)(src + j);
}

#define FMA16(WPTR) do {                                              \
    const float4 wa = *(const float4*)((WPTR) + o0);                  \
    const float4 wb = *(const float4*)((WPTR) + o0 + 4);              \
    const float4 wc = *(const float4*)((WPTR) + o0 + 64);             \
    const float4 wd = *(const float4*)((WPTR) + o0 + 68);             \
    acc[0]=fmaf(v,wa.x,acc[0]);  acc[1]=fmaf(v,wa.y,acc[1]);          \
    acc[2]=fmaf(v,wa.z,acc[2]);  acc[3]=fmaf(v,wa.w,acc[3]);          \
    acc[4]=fmaf(v,wb.x,acc[4]);  acc[5]=fmaf(v,wb.y,acc[5]);          \
    acc[6]=fmaf(v,wb.z,acc[6]);  acc[7]=fmaf(v,wb.w,acc[7]);          \
    acc[8]=fmaf(v,wc.x,acc[8]);  acc[9]=fmaf(v,wc.y,acc[9]);          \
    acc[10]=fmaf(v,wc.z,acc[10]); acc[11]=fmaf(v,wc.w,acc[11]);       \
    acc[12]=fmaf(v,wd.x,acc[12]); acc[13]=fmaf(v,wd.y,acc[13]);       \
    acc[14]=fmaf(v,wd.z,acc[14]); acc[15]=fmaf(v,wd.w,acc[15]);       \
  } while (0)

__global__ __launch_bounds__(256) void fused_kernel(
    const float* __restrict__ xyz, const float* __restrict__ points,
    const int* __restrict__ fps_idx, const int* __restrict__ group_idx,
    float* __restrict__ out)
{
  const float* __restrict__ W = g_W;
  __shared__ __align__(16) float SH[SH_FLOATS];
  float* sA   = SH + OFF_A;
  float* sB   = SH + OFF_B;
  float* sE   = SH + OFF_E;
  float* sH3  = SH + OFF_H3;
  float* wbuf = SH + OFF_WB;
  float* sFps = SH + OFF_FPS;
  float* sRx  = SH + OFF_RX;
  float* sF1  = SH + OFF_F1;
  float* sF2  = SH + OFF_F2;
  float* sF3  = SH + OFF_F3;
  float* sEb  = SH + OFF_EB;

  const int t = threadIdx.x;
  const int bp = blockIdx.x;
  const int b = bp >> 10;
  const int p = bp & 1023;

  // -------- Phase 0a: stage W1 + fps point --------
  stage(wbuf, W + W1T_OFF, 4288, t);
  if (t < 67) {
    const int fi = fps_idx[b * Pn + p];
    float v;
    if (t < 3) v = xyz[b * 3 * Nn + t * Nn + fi];
    else       v = points[b * Cn * Nn + (t - 3) * Nn + fi];
    sFps[t] = v;
  }
  __syncthreads();

  // -------- Phase 0b: gather neighbors (rel xyz || feat) --------
  {
    const int s0 = t >> 3, cg = t & 7;
    const int gi = group_idx[(b * Pn + p) * Sn + s0];
    const float* prow = points + b * Cn * Nn + gi;
    const int c0 = cg * 8;
    #pragma unroll
    for (int k = 0; k < 8; ++k)
      sA[s0 * 69 + 3 + c0 + k] = prow[(c0 + k) * Nn];
    if (cg == 0) {
      #pragma unroll
      for (int d = 0; d < 3; ++d) {
        const float r = xyz[b * 3 * Nn + d * Nn + gi] - sFps[d];
        sA[s0 * 69 + d] = r;
        sRx[s0 * 3 + d] = r;
      }
    }
  }
  __syncthreads();

  const int s = t & 31;
  const int og = t >> 5;
  const int o0 = og * 8;

  // -------- Phase 1: layer1 (67 -> 64), relu. Weights in wbuf --------
  {
    float acc[8];
    {
      const float4 bb0 = *(const float4*)(W + B1_OFF + o0);
      const float4 bb1 = *(const float4*)(W + B1_OFF + o0 + 4);
      acc[0] = bb0.x; acc[1] = bb0.y; acc[2] = bb0.z; acc[3] = bb0.w;
      acc[4] = bb1.x; acc[5] = bb1.y; acc[6] = bb1.z; acc[7] = bb1.w;
    }
    #pragma unroll 4
    for (int i = 0; i < 67; ++i) {
      const float v = sA[s * 69 + i];
      const float4 wa = *(const float4*)(wbuf + i * 64 + o0);
      const float4 wb = *(const float4*)(wbuf + i * 64 + o0 + 4);
      acc[0] = fmaf(v, wa.x, acc[0]); acc[1] = fmaf(v, wa.y, acc[1]);
      acc[2] = fmaf(v, wa.z, acc[2]); acc[3] = fmaf(v, wa.w, acc[3]);
      acc[4] = fmaf(v, wb.x, acc[4]); acc[5] = fmaf(v, wb.y, acc[5]);
      acc[6] = fmaf(v, wb.z, acc[6]); acc[7] = fmaf(v, wb.w, acc[7]);
    }
    #pragma unroll
    for (int k = 0; k < 8; ++k) sB[s * 65 + o0 + k] = fmaxf(acc[k], 0.f);
  }
  if (t < 64) {  // fps row, layer1
    float acc = W[B1_OFF + t];
    for (int i = 0; i < 67; ++i) acc = fmaf(sFps[i], wbuf[i * 64 + t], acc);
    sF1[t] = fmaxf(acc, 0.f);
  }
  __syncthreads();   // h1/sF1 ready; wbuf free

  // -------- Phase 2: layer2 (64 -> 64), relu --------
  stage(wbuf, W + W2T_OFF, 4096, t);
  __syncthreads();
  {
    float acc[8];
    {
      const float4 bb0 = *(const float4*)(W + B2_OFF + o0);
      const float4 bb1 = *(const float4*)(W + B2_OFF + o0 + 4);
      acc[0] = bb0.x; acc[1] = bb0.y; acc[2] = bb0.z; acc[3] = bb0.w;
      acc[4] = bb1.x; acc[5] = bb1.y; acc[6] = bb1.z; acc[7] = bb1.w;
    }
    #pragma unroll 4
    for (int i = 0; i < 64; ++i) {
      const float v = sB[s * 65 + i];
      const float4 wa = *(const float4*)(wbuf + i * 64 + o0);
      const float4 wb = *(const float4*)(wbuf + i * 64 + o0 + 4);
      acc[0] = fmaf(v, wa.x, acc[0]); acc[1] = fmaf(v, wa.y, acc[1]);
      acc[2] = fmaf(v, wa.z, acc[2]); acc[3] = fmaf(v, wa.w, acc[3]);
      acc[4] = fmaf(v, wb.x, acc[4]); acc[5] = fmaf(v, wb.y, acc[5]);
      acc[6] = fmaf(v, wb.z, acc[6]); acc[7] = fmaf(v, wb.w, acc[7]);
    }
    #pragma unroll
    for (int k = 0; k < 8; ++k) sA[s * 65 + o0 + k] = fmaxf(acc[k], 0.f);
  }
  if (t < 64) {
    float acc = W[B2_OFF + t];
    for (int i = 0; i < 64; ++i) acc = fmaf(sF1[i], wbuf[i * 64 + t], acc);
    sF2[t] = fmaxf(acc, 0.f);
  }
  __syncthreads();   // h2/sF2 ready; wbuf free

  // -------- Phase 3: layer3 (64 -> 128), K chunked 2x32 --------
  {
    float acc[16];
    {
      const float4 b0 = *(const float4*)(W + B3_OFF + o0);
      const float4 b1 = *(const float4*)(W + B3_OFF + o0 + 4);
      const float4 b2 = *(const float4*)(W + B3_OFF + o0 + 64);
      const float4 b3 = *(const float4*)(W + B3_OFF + o0 + 68);
      acc[0]=b0.x; acc[1]=b0.y; acc[2]=b0.z; acc[3]=b0.w;
      acc[4]=b1.x; acc[5]=b1.y; acc[6]=b1.z; acc[7]=b1.w;
      acc[8]=b2.x; acc[9]=b2.y; acc[10]=b2.z; acc[11]=b2.w;
      acc[12]=b3.x; acc[13]=b3.y; acc[14]=b3.z; acc[15]=b3.w;
    }
    float accF = (t < 128) ? W[B3_OFF + t] : 0.f;
    for (int c = 0; c < 2; ++c) {
      stage(wbuf, W + W3T_OFF + c * 4096, 4096, t);
      __syncthreads();
      #pragma unroll 2
      for (int i = 0; i < 32; ++i) {
        const float v = sA[s * 65 + c * 32 + i];
        FMA16(wbuf + i * 128);
      }
      if (t < 128)
        for (int i = 0; i < 32; ++i)
          accF = fmaf(sF2[c * 32 + i], wbuf[i * 128 + t], accF);
      __syncthreads();  // wbuf free
    }
    #pragma unroll
    for (int k = 0; k < 8; ++k) {
      sH3[s * 129 + o0 + k]      = fmaxf(acc[k], 0.f);
      sH3[s * 129 + o0 + 64 + k] = fmaxf(acc[8 + k], 0.f);
    }
    if (t < 128) sF3[t] = fmaxf(accF, 0.f);
  }
  // NOTE: no sync needed yet — next is staging into free wbuf; sH3/sF3
  // consumers wait at the stage sync below.

  // -------- Phase 5 (+ fused ebias): e-scores, K chunked 35+3x32 --------
  {
    float acc[16];
    #pragma unroll
    for (int k = 0; k < 16; ++k) acc[k] = 0.f;
    float accEb = 0.f;

    // chunk 0: rows 0..34 (3 xyz rows + 32 h3 rows)
    stage(wbuf, W + AT_OFF, 35 * 128, t);
    __syncthreads();  // wbuf + sH3/sF3 ready
    #pragma unroll
    for (int i = 0; i < 3; ++i) {
      const float v = sRx[s * 3 + i];
      FMA16(wbuf + i * 128);
    }
    #pragma unroll 2
    for (int i = 3; i < 35; ++i) {
      const float v = sH3[s * 129 + i - 3];
      FMA16(wbuf + i * 128);
    }
    if (t < 128) {
      #pragma unroll
      for (int i = 0; i < 3; ++i)  accEb = fmaf(sFps[i], wbuf[i * 128 + t], accEb);
      for (int i = 3; i < 35; ++i) accEb = fmaf(sF3[i - 3], wbuf[i * 128 + t], accEb);
    }
    __syncthreads();

    // chunks 1..3: 32 rows each
    for (int c = 0; c < 3; ++c) {
      const int k0 = 35 + 32 * c;
      stage(wbuf, W + AT_OFF + k0 * 128, 32 * 128, t);
      __syncthreads();
      #pragma unroll 2
      for (int i = 0; i < 32; ++i) {
        const float v = sH3[s * 129 + k0 - 3 + i];
        FMA16(wbuf + i * 128);
      }
      if (t < 128)
        for (int i = 0; i < 32; ++i)
          accEb = fmaf(sF3[k0 - 3 + i], wbuf[i * 128 + t], accEb);
      __syncthreads();
    }

    if (t < 128) sEb[t] = accEb;
    __syncthreads();

    #pragma unroll
    for (int k = 0; k < 8; ++k) {
      float e0 = sEb[o0 + k] - acc[k];
      e0 = (e0 > 0.f) ? e0 : ALPHAn * e0;
      sE[s * 129 + o0 + k] = e0;
      float e1 = sEb[o0 + 64 + k] - acc[8 + k];
      e1 = (e1 > 0.f) ? e1 : ALPHAn * e1;
      sE[s * 129 + o0 + 64 + k] = e1;
    }
  }
  __syncthreads();

  // -------- Phase 6: column softmax over s + pooled sum; outputs --------
  if (t < 128) {
    const int j = t;
    float mx = -3.4e38f;
    for (int si = 0; si < 32; ++si) mx = fmaxf(mx, sE[si * 129 + j]);
    float den = 0.f, pool = 0.f;
    for (int si = 0; si < 32; ++si) {
      const float wv = __expf(sE[si * 129 + j] - mx);
      den += wv;
      pool = fmaf(wv, sH3[si * 129 + j], pool);
    }
    out[Bn * 3 * Pn + (b * 128 + j) * Pn + p] = pool / den;
  } else if (t < 131) {
    const int d = t - 128;
    out[(b * 3 + d) * Pn + p] = sFps[d];
  }
}

extern "C" void kernel_launch(void* const* d_in, const int* in_sizes, int n_in,
                              void* d_out, int out_size, void* d_ws, size_t ws_size,
                              hipStream_t stream) {
  const float* xyz       = (const float*)d_in[0];
  const float* points    = (const float*)d_in[1];
  const int*   fps_idx   = (const int*)d_in[2];
  const int*   group_idx = (const int*)d_in[3];

  prep_kernel<<<(WS_FLOATS + 255) / 256, 256, 0, stream>>>(
      (const float*)d_in[4],  (const float*)d_in[5],
      (const float*)d_in[6],  (const float*)d_in[7],
      (const float*)d_in[8],  (const float*)d_in[9],
      (const float*)d_in[10], (const float*)d_in[11],
      (const float*)d_in[12], (const float*)d_in[13],
      (const float*)d_in[14], (const float*)d_in[15],
      (const float*)d_in[16], (const float*)d_in[17],
      (const float*)d_in[18], (const float*)d_in[19],
      (const float*)d_in[20], (const float*)d_in[21],
      (const float*)d_in[22]);

  fused_kernel<<<Bn * Pn, 256, 0, stream>>>(xyz, points, fps_idx, group_idx,
                                            (float*)d_out);
}

// Round 6
// 897.672 us; speedup vs baseline: 2.3260x; 1.2274x over previous
//
#include <hip/hip_runtime.h>
#include <hip/hip_bf16.h>

// Problem constants (fixed by setup_inputs)
#define Bn 16
#define Nn 4096
#define Pn 1024
#define Sn 32
#define Cn 64
#define EPSn 1e-5f
#define ALPHAn 0.2f

// Folded-weight table in module device memory.
#define W1T_OFF 0      // [67][64]
#define B1_OFF  4288   // [64]
#define W2T_OFF 4352   // [64][64]
#define B2_OFF  8448   // [64]
#define W3T_OFF 8512   // [64][128]
#define B3_OFF  16704  // [128]
#define AT_OFF  16832  // [131][128]
#define WS_FLOATS 33600

__device__ __align__(16) float g_W[WS_FLOATS];

__global__ void prep_kernel(
    const float* __restrict__ w1, const float* __restrict__ b1,
    const float* __restrict__ g1, const float* __restrict__ bt1,
    const float* __restrict__ m1, const float* __restrict__ v1,
    const float* __restrict__ w2, const float* __restrict__ b2,
    const float* __restrict__ g2, const float* __restrict__ bt2,
    const float* __restrict__ m2, const float* __restrict__ v2,
    const float* __restrict__ w3, const float* __restrict__ b3,
    const float* __restrict__ g3, const float* __restrict__ bt3,
    const float* __restrict__ m3, const float* __restrict__ v3,
    const float* __restrict__ a)
{
  float* __restrict__ W = g_W;
  const int idx = blockIdx.x * blockDim.x + threadIdx.x;
  if (idx >= WS_FLOATS) return;
  if (idx < B1_OFF) {
    const int i = idx >> 6, o = idx & 63;
    const float s = g1[o] * rsqrtf(v1[o] + EPSn);
    W[idx] = w1[o * 67 + i] * s;
  } else if (idx < W2T_OFF) {
    const int o = idx - B1_OFF;
    const float s = g1[o] * rsqrtf(v1[o] + EPSn);
    W[idx] = (b1[o] - m1[o]) * s + bt1[o];
  } else if (idx < B2_OFF) {
    const int r = idx - W2T_OFF;
    const int i = r >> 6, o = r & 63;
    const float s = g2[o] * rsqrtf(v2[o] + EPSn);
    W[idx] = w2[o * 64 + i] * s;
  } else if (idx < W3T_OFF) {
    const int o = idx - B2_OFF;
    const float s = g2[o] * rsqrtf(v2[o] + EPSn);
    W[idx] = (b2[o] - m2[o]) * s + bt2[o];
  } else if (idx < B3_OFF) {
    const int r = idx - W3T_OFF;
    const int i = r >> 7, o = r & 127;
    const float s = g3[o] * rsqrtf(v3[o] + EPSn);
    W[idx] = w3[o * 64 + i] * s;
  } else if (idx < AT_OFF) {
    const int o = idx - B3_OFF;
    const float s = g3[o] * rsqrtf(v3[o] + EPSn);
    W[idx] = (b3[o] - m3[o]) * s + bt3[o];
  } else {
    W[idx] = a[idx - AT_OFF];
  }
}

// LDS layout (floats). Keep total <= ~13100 floats (52.4 KB) for 3 blocks/CU
// (R5 lesson: 54272 B dropped residency to 2 blocks, occupancy 35%->23%).
#define OFF_A    0      // 2208: phase-1 input (stride 69); reused as h2 (stride 65)
#define OFF_B    2208   // 2080: h1 (stride 65)
#define OFF_E    0      // sE (4128) aliases dead sA+sB region in phase 5/6
#define OFF_H3   4288   // 4128
#define OFF_WB0  8416   // 2048 (16B aligned: 33664 B)
#define OFF_WB1  10464  // 2048 (41856 B)
#define OFF_FPS  12512  // 68
#define OFF_RX   12580  // 96
#define OFF_F1   12676  // 64
#define OFF_F2   12740  // 64
#define OFF_F3   12804  // 128
#define OFF_EB   12932  // 128
#define SH_FLOATS 13060 // 52240 B -> 3 blocks/CU

// Async global->LDS staging. Pattern is wave-uniform base + lane*16B
// (prefix-active lanes on tails keep lane0 active per wave).
__device__ __forceinline__ void stage_async(const float* src, float* dst,
                                            int count, int t) {
  #pragma unroll
  for (int j = 0; j < count; j += 1024) {
    if (4 * t < count - j) {
      __builtin_amdgcn_global_load_lds(
          (const __attribute__((address_space(1))) void*)(src + j + 4 * t),
          (__attribute__((address_space(3))) void*)(dst + j + 4 * t),
          16, 0, 0);
    }
  }
}

#define FMA8(WPTR) do {                                               \
    const float4 wa = *(const float4*)((WPTR) + o0);                  \
    const float4 wb = *(const float4*)((WPTR) + o0 + 4);              \
    acc[0]=fmaf(v,wa.x,acc[0]);  acc[1]=fmaf(v,wa.y,acc[1]);          \
    acc[2]=fmaf(v,wa.z,acc[2]);  acc[3]=fmaf(v,wa.w,acc[3]);          \
    acc[4]=fmaf(v,wb.x,acc[4]);  acc[5]=fmaf(v,wb.y,acc[5]);          \
    acc[6]=fmaf(v,wb.z,acc[6]);  acc[7]=fmaf(v,wb.w,acc[7]);          \
  } while (0)

#define FMA16(WPTR) do {                                              \
    const float4 wa = *(const float4*)((WPTR) + o0);                  \
    const float4 wb = *(const float4*)((WPTR) + o0 + 4);              \
    const float4 wc = *(const float4*)((WPTR) + o0 + 64);             \
    const float4 wd = *(const float4*)((WPTR) + o0 + 68);             \
    acc[0]=fmaf(v,wa.x,acc[0]);  acc[1]=fmaf(v,wa.y,acc[1]);          \
    acc[2]=fmaf(v,wa.z,acc[2]);  acc[3]=fmaf(v,wa.w,acc[3]);          \
    acc[4]=fmaf(v,wb.x,acc[4]);  acc[5]=fmaf(v,wb.y,acc[5]);          \
    acc[6]=fmaf(v,wb.z,acc[6]);  acc[7]=fmaf(v,wb.w,acc[7]);          \
    acc[8]=fmaf(v,wc.x,acc[8]);  acc[9]=fmaf(v,wc.y,acc[9]);          \
    acc[10]=fmaf(v,wc.z,acc[10]); acc[11]=fmaf(v,wc.w,acc[11]);       \
    acc[12]=fmaf(v,wd.x,acc[12]); acc[13]=fmaf(v,wd.y,acc[13]);       \
    acc[14]=fmaf(v,wd.z,acc[14]); acc[15]=fmaf(v,wd.w,acc[15]);       \
  } while (0)

// Pipeline: step c = { issue chunk c+1 -> wb[(c+1)&1]; compute chunk c from
// wb[c&1]; __syncthreads() }. The barrier's vmcnt drain costs ~0 because the
// load had a full compute-chunk to land; the barrier also protects buffer reuse.
__global__ __launch_bounds__(256) void fused_kernel(
    const float* __restrict__ xyz, const float* __restrict__ points,
    const int* __restrict__ fps_idx, const int* __restrict__ group_idx,
    float* __restrict__ out)
{
  const float* __restrict__ W = g_W;
  __shared__ __align__(16) float SH[SH_FLOATS];
  float* sA   = SH + OFF_A;
  float* sB   = SH + OFF_B;
  float* sE   = SH + OFF_E;
  float* sH3  = SH + OFF_H3;
  float* wb0  = SH + OFF_WB0;
  float* wb1  = SH + OFF_WB1;
  float* sFps = SH + OFF_FPS;
  float* sRx  = SH + OFF_RX;
  float* sF1  = SH + OFF_F1;
  float* sF2  = SH + OFF_F2;
  float* sF3  = SH + OFF_F3;
  float* sEb  = SH + OFF_EB;

  const int t = threadIdx.x;
  const int b = blockIdx.x >> 10;
  const int p = blockIdx.x & 1023;
  const int s = t & 31;
  const int og = t >> 5;
  const int o0 = og * 8;
  const int tf  = t & 63;   // fps-row output idx, layers 1/2 (redundant across waves)
  const int tf1 = t & 127;  // fps-row output idx, layer 3 / ebias

  // ---- prologue: issue chunk0 (W1 rows 0-31); load fps point ----
  stage_async(W + W1T_OFF, wb0, 2048, t);
  if (t < 67) {
    const int fi = fps_idx[b * Pn + p];
    sFps[t] = (t < 3) ? xyz[b * 3 * Nn + t * Nn + fi]
                      : points[b * Cn * Nn + (t - 3) * Nn + fi];
  }
  // hoisted bias registers (L2-hot; overlap with gather)
  float bias1[8];
  {
    const float4 x0 = *(const float4*)(W + B1_OFF + o0);
    const float4 x1 = *(const float4*)(W + B1_OFF + o0 + 4);
    bias1[0]=x0.x; bias1[1]=x0.y; bias1[2]=x0.z; bias1[3]=x0.w;
    bias1[4]=x1.x; bias1[5]=x1.y; bias1[6]=x1.z; bias1[7]=x1.w;
  }
  const float biasF1 = W[B1_OFF + tf];
  __syncthreads();

  // ---- issue chunk1 (W1 rows 32-63); gather neighbors ----
  stage_async(W + W1T_OFF + 2048, wb1, 2048, t);
  {
    const int s0 = t >> 3, cg = t & 7;
    const int gi = group_idx[(b * Pn + p) * Sn + s0];
    const float* prow = points + b * Cn * Nn + gi;
    const int c0 = cg * 8;
    #pragma unroll
    for (int k = 0; k < 8; ++k)
      sA[s0 * 69 + 3 + c0 + k] = prow[(c0 + k) * Nn];
    if (cg == 0) {
      #pragma unroll
      for (int d = 0; d < 3; ++d) {
        const float r = xyz[b * 3 * Nn + d * Nn + gi] - sFps[d];
        sA[s0 * 69 + d] = r;
        sRx[s0 * 3 + d] = r;
      }
    }
  }
  __syncthreads();  // chunk0+chunk1 landed; gather visible

  float acc[16];
  float accF;

  // ===== Phase 1: layer1 (67 -> 64), chunks 0..2 =====
  #pragma unroll
  for (int k = 0; k < 8; ++k) acc[k] = bias1[k];
  accF = biasF1;
  float bias2[8];
  {
    const float4 x0 = *(const float4*)(W + B2_OFF + o0);
    const float4 x1 = *(const float4*)(W + B2_OFF + o0 + 4);
    bias2[0]=x0.x; bias2[1]=x0.y; bias2[2]=x0.z; bias2[3]=x0.w;
    bias2[4]=x1.x; bias2[5]=x1.y; bias2[6]=x1.z; bias2[7]=x1.w;
  }
  const float biasF2 = W[B2_OFF + tf];

  // step 0: compute W1 rows 0..31 (wb0)   [chunk1 already in flight]
  #pragma unroll 4
  for (int i = 0; i < 32; ++i) {
    const float v = sA[s * 69 + i];
    FMA8(wb0 + i * 64);
    accF = fmaf(sFps[i], wb0[i * 64 + tf], accF);
  }
  __syncthreads();

  // step 1: issue chunk2 (W1 rows 64-66); compute rows 32..63 (wb1)
  stage_async(W + W1T_OFF + 4096, wb0, 192, t);
  #pragma unroll 4
  for (int i = 0; i < 32; ++i) {
    const float v = sA[s * 69 + 32 + i];
    FMA8(wb1 + i * 64);
    accF = fmaf(sFps[32 + i], wb1[i * 64 + tf], accF);
  }
  __syncthreads();

  // step 2: issue chunk3 (W2 rows 0-31); compute rows 64..66 (wb0); write h1
  stage_async(W + W2T_OFF, wb1, 2048, t);
  #pragma unroll
  for (int i = 0; i < 3; ++i) {
    const float v = sA[s * 69 + 64 + i];
    FMA8(wb0 + i * 64);
    accF = fmaf(sFps[64 + i], wb0[i * 64 + tf], accF);
  }
  #pragma unroll
  for (int k = 0; k < 8; ++k) sB[s * 65 + o0 + k] = fmaxf(acc[k], 0.f);
  if (t < 64) sF1[t] = fmaxf(accF, 0.f);
  __syncthreads();

  // ===== Phase 2: layer2 (64 -> 64), chunks 3..4 =====
  #pragma unroll
  for (int k = 0; k < 8; ++k) acc[k] = bias2[k];
  accF = biasF2;
  float bias3[16];
  {
    const float4 x0 = *(const float4*)(W + B3_OFF + o0);
    const float4 x1 = *(const float4*)(W + B3_OFF + o0 + 4);
    const float4 x2 = *(const float4*)(W + B3_OFF + o0 + 64);
    const float4 x3 = *(const float4*)(W + B3_OFF + o0 + 68);
    bias3[0]=x0.x;  bias3[1]=x0.y;  bias3[2]=x0.z;  bias3[3]=x0.w;
    bias3[4]=x1.x;  bias3[5]=x1.y;  bias3[6]=x1.z;  bias3[7]=x1.w;
    bias3[8]=x2.x;  bias3[9]=x2.y;  bias3[10]=x2.z; bias3[11]=x2.w;
    bias3[12]=x3.x; bias3[13]=x3.y; bias3[14]=x3.z; bias3[15]=x3.w;
  }
  const float biasF3 = W[B3_OFF + tf1];

  // step 3: issue chunk4 (W2 rows 32-63); compute rows 0..31 (wb1)
  stage_async(W + W2T_OFF + 2048, wb0, 2048, t);
  #pragma unroll 4
  for (int i = 0; i < 32; ++i) {
    const float v = sB[s * 65 + i];
    FMA8(wb1 + i * 64);
    accF = fmaf(sF1[i], wb1[i * 64 + tf], accF);
  }
  __syncthreads();

  // step 4: issue chunk5 (W3 rows 0-15); compute rows 32..63 (wb0); write h2
  stage_async(W + W3T_OFF, wb1, 2048, t);
  #pragma unroll 4
  for (int i = 0; i < 32; ++i) {
    const float v = sB[s * 65 + 32 + i];
    FMA8(wb0 + i * 64);
    accF = fmaf(sF1[32 + i], wb0[i * 64 + tf], accF);
  }
  #pragma unroll
  for (int k = 0; k < 8; ++k) sA[s * 65 + o0 + k] = fmaxf(acc[k], 0.f);
  if (t < 64) sF2[t] = fmaxf(accF, 0.f);
  __syncthreads();

  // ===== Phase 3: layer3 (64 -> 128), chunks 5..8 (16 rows x 128) =====
  #pragma unroll
  for (int k = 0; k < 16; ++k) acc[k] = bias3[k];
  accF = biasF3;
  #pragma unroll
  for (int cc = 0; cc < 4; ++cc) {
    float* wr = ((5 + cc) & 1) ? wb1 : wb0;
    float* wn = ((5 + cc) & 1) ? wb0 : wb1;
    if (cc < 3) stage_async(W + W3T_OFF + (cc + 1) * 2048, wn, 2048, t);
    else        stage_async(W + AT_OFF + 3 * 128, wn, 2048, t);  // chunk9 = A rows 3..18
    #pragma unroll 2
    for (int i = 0; i < 16; ++i) {
      const float v = sA[s * 65 + cc * 16 + i];
      FMA16(wr + i * 128);
      accF = fmaf(sF2[cc * 16 + i], wr[i * 128 + tf1], accF);
    }
    if (cc == 3) {  // write h3 / fps3 before the barrier; phase-5 reads after it
      #pragma unroll
      for (int k = 0; k < 8; ++k) {
        sH3[s * 129 + o0 + k]      = fmaxf(acc[k], 0.f);
        sH3[s * 129 + o0 + 64 + k] = fmaxf(acc[8 + k], 0.f);
      }
      if (t < 128) sF3[t] = fmaxf(accF, 0.f);
    }
    __syncthreads();
  }

  // ===== Phase 5: attention scores, chunks 9..16 (A rows 3+16j) + 17 (rows 0-2) =====
  #pragma unroll
  for (int k = 0; k < 16; ++k) acc[k] = 0.f;
  float accEb = 0.f;
  #pragma unroll
  for (int j = 0; j < 8; ++j) {
    float* wr = ((9 + j) & 1) ? wb1 : wb0;
    float* wn = ((9 + j) & 1) ? wb0 : wb1;
    if (j < 7) stage_async(W + AT_OFF + (3 + 16 * (j + 1)) * 128, wn, 2048, t);
    else       stage_async(W + AT_OFF, wn, 384, t);              // chunk17: rows 0..2
    #pragma unroll 2
    for (int i = 0; i < 16; ++i) {
      const float v = sH3[s * 129 + 16 * j + i];
      FMA16(wr + i * 128);
      accEb = fmaf(sF3[16 * j + i], wr[i * 128 + tf1], accEb);
    }
    __syncthreads();
  }
  // step 17: xyz part (3 rows) from wb1
  #pragma unroll
  for (int i = 0; i < 3; ++i) {
    const float v = sRx[s * 3 + i];
    FMA16(wb1 + i * 128);
    accEb = fmaf(sFps[i], wb1[i * 128 + tf1], accEb);
  }
  if (t < 128) sEb[t] = accEb;
  __syncthreads();

  // e = leakyrelu(ebias - acc) -> sE (aliases dead sA/sB region)
  #pragma unroll
  for (int k = 0; k < 8; ++k) {
    float e0 = sEb[o0 + k] - acc[k];
    e0 = (e0 > 0.f) ? e0 : ALPHAn * e0;
    sE[s * 129 + o0 + k] = e0;
    float e1 = sEb[o0 + 64 + k] - acc[8 + k];
    e1 = (e1 > 0.f) ? e1 : ALPHAn * e1;
    sE[s * 129 + o0 + 64 + k] = e1;
  }
  __syncthreads();

  // ===== Phase 6: column softmax over s + pooled sum; outputs =====
  if (t < 128) {
    const int j = t;
    float mx = -3.4e38f;
    for (int si = 0; si < 32; ++si) mx = fmaxf(mx, sE[si * 129 + j]);
    float den = 0.f, pool = 0.f;
    for (int si = 0; si < 32; ++si) {
      const float wv = __expf(sE[si * 129 + j] - mx);
      den += wv;
      pool = fmaf(wv, sH3[si * 129 + j], pool);
    }
    out[Bn * 3 * Pn + (b * 128 + j) * Pn + p] = pool / den;
  } else if (t < 131) {
    const int d = t - 128;
    out[(b * 3 + d) * Pn + p] = sFps[d];
  }
}

extern "C" void kernel_launch(void* const* d_in, const int* in_sizes, int n_in,
                              void* d_out, int out_size, void* d_ws, size_t ws_size,
                              hipStream_t stream) {
  const float* xyz       = (const float*)d_in[0];
  const float* points    = (const float*)d_in[1];
  const int*   fps_idx   = (const int*)d_in[2];
  const int*   group_idx = (const int*)d_in[3];

  prep_kernel<<<(WS_FLOATS + 255) / 256, 256, 0, stream>>>(
      (const float*)d_in[4],  (const float*)d_in[5],
      (const float*)d_in[6],  (const float*)d_in[7],
      (const float*)d_in[8],  (const float*)d_in[9],
      (const float*)d_in[10], (const float*)d_in[11],
      (const float*)d_in[12], (const float*)d_in[13],
      (const float*)d_in[14], (const float*)d_in[15],
      (const float*)d_in[16], (const float*)d_in[17],
      (const float*)d_in[18], (const float*)d_in[19],
      (const float*)d_in[20], (const float*)d_in[21],
      (const float*)d_in[22]);

  fused_kernel<<<Bn * Pn, 256, 0, stream>>>(xyz, points, fps_idx, group_idx,
                                            (float*)d_out);
}